// Round 9
// baseline (2002.887 us; speedup 1.0000x reference)
//
#include <hip/hip_runtime.h>
#include <stdint.h>
#include <math.h>

// ---------------- problem constants ----------------
#define BB 32
#define TT 1024
#define CIN 128
#define FF 256
#define KW 5
#define HH 512
#define TP 510          // conv output length (VALID, stride 2)
#define TLAST 509
#define KC 640          // conv GEMM K  (5*128)
#define GWG 64          // scan workgroups: 2 groups x 32 wgs

// ---------------- workspace layout (bytes) ----------------
// parts words tagged (tag<<32|payload): 0xAA poison never matches tags 1..510.
// h words u32 (hi16|lo16) with lo LSB = generation marker ((s>>1)&1)^1 —
// consumer validates markers after the bulk load, so the producer needs NO
// store-ack fence, and consumers may load SPECULATIVELY before detection.
#define HPK_OFF     0ull          // h u32: [2 grp][par2][16 b][512 u] = 131072 (region reserves 262144)
#define PRT_OFF     262144ull     // parts u64: [2 grp][par2][16 b][32 slot] = 16384
#define XP_OFF      278528ull                         // fp32 [2grp][512 t'][32 sl][4q][16bb][16jj] = 134217728
#define XH_OFF      (XP_OFF + 134217728ull)           // x hi bf16 [4194304]
#define XL_OFF      (XH_OFF + 8388608ull)
#define XSH_OFF     (XL_OFF + 8388608ull)             // xs hi bf16 [16384][256]
#define XSL_OFF     (XSH_OFF + 8388608ull)
#define WCH_OFF     (XSL_OFF + 8388608ull)            // conv W [256][640] hi
#define WCL_OFF     (WCH_OFF + 327680ull)
#define WIHH_OFF    (WCL_OFF + 327680ull)             // w_ih [2048][256] hi
#define WIHL_OFF    (WIHH_OFF + 1048576ull)
#define WS_NEED     (WIHL_OFF + 1048576ull)           // ~163.6 MiB (unchanged)

typedef unsigned short u16;
typedef unsigned long long u64;
typedef __attribute__((ext_vector_type(8))) short short8;
typedef __attribute__((ext_vector_type(4))) float f32x4;
typedef __attribute__((ext_vector_type(4))) unsigned int u32x4;

#define AL(p) __hip_atomic_load((p), __ATOMIC_RELAXED, __HIP_MEMORY_SCOPE_AGENT)

__device__ __forceinline__ u16 f2bf(float f) {
  uint32_t u = __float_as_uint(f);
  u += 0x7fffu + ((u >> 16) & 1u);      // RNE
  return (u16)(u >> 16);
}
__device__ __forceinline__ float bf2f(u16 s) { return __uint_as_float(((uint32_t)s) << 16); }
__device__ __forceinline__ void splitf(float v, u16& h, u16& l) {
  h = f2bf(v);
  l = f2bf(v - bf2f(h));
}
// fast transcendentals (v_exp_f32 path, ~1 ulp): keeps the scan epilogue's
// critical path free of branchy libm calls. Gate perturbation ~1e-6 << margin.
__device__ __forceinline__ float sigm(float x) {
  return __fdividef(1.f, 1.f + __expf(-x));
}
__device__ __forceinline__ float tanh_fast(float x) {
  float xc = fminf(x, 20.f);             // avoid inf/inf for large +x (tanh==1 there)
  float e = __expf(2.f * xc);
  return (e - 1.f) * __fdividef(1.f, e + 1.f);
}

// ---------------- prep: split x / conv_w(transposed) / w_ih into bf16 hi+lo ----------------
__global__ void prep_kernel(const float* __restrict__ x, const float* __restrict__ conv_w,
                            const float* __restrict__ w_ih,
                            u16* __restrict__ xh, u16* __restrict__ xl,
                            u16* __restrict__ wch, u16* __restrict__ wcl,
                            u16* __restrict__ wihh, u16* __restrict__ wihl) {
  int i = blockIdx.x * 256 + threadIdx.x;
  if (i < 4194304) {
    u16 h, l; splitf(x[i], h, l); xh[i] = h; xl[i] = l;
  } else if (i < 4194304 + 163840) {
    int j = i - 4194304;
    int f = j / 640, kk = j % 640;
    int c = kk & 127, k = kk >> 7;                 // kk = k*128 + c
    u16 h, l; splitf(conv_w[f * 640 + c * 5 + k], h, l);
    wch[f * 640 + kk] = h; wcl[f * 640 + kk] = l;
  } else if (i < 4194304 + 163840 + 524288) {
    int j = i - (4194304 + 163840);
    u16 h, l; splitf(w_ih[j], h, l); wihh[j] = h; wihl[j] = l;
  }
}

// ---------------- split-bf16 GEMM, 128x128 tile, BK=32, frag-order LDS ----------------
// MODE 0: conv  (K=640, B = windowed x, epilogue relu+BN -> xs hi/lo bf16 at [n][f])
// MODE 1: proj  (K=256, B = xs rows,    epilogue +bias   -> xp fp32, scan-coalesced layout)
template <int MODE>
__global__ __launch_bounds__(256, 1) void gemm_kernel(
    const u16* __restrict__ Ah, const u16* __restrict__ Al,
    const u16* __restrict__ Bh, const u16* __restrict__ Bl,
    const float* __restrict__ e0, const float* __restrict__ e1,
    const float* __restrict__ e2, const float* __restrict__ e3, const float* __restrict__ e4,
    u16* __restrict__ outh, u16* __restrict__ outl, float* __restrict__ outf) {
  const int KDIM = (MODE == 0) ? KC : 256;
  const int MT   = (MODE == 0) ? 2 : 16;
  int bx = blockIdx.x;
  int m0 = (bx % MT) * 128;
  int n0 = (bx / MT) * 128;
  __shared__ __attribute__((aligned(16))) u16 lds[4][4096];
  int t = threadIdx.x;
  int wave = t >> 6, lane = t & 63;
  int wm = wave & 1, wn = wave >> 1;

  f32x4 acc[4][4];
#pragma unroll
  for (int i = 0; i < 4; i++)
#pragma unroll
    for (int j = 0; j < 4; j++) acc[i][j] = (f32x4){0.f, 0.f, 0.f, 0.f};

  for (int k0 = 0; k0 < KDIM; k0 += 32) {
    __syncthreads();
#pragma unroll
    for (int half = 0; half < 2; half++) {
      int e = half * 256 + t;
      int l = e & 63, tile = e >> 6;
      int kk = k0 + ((l >> 4) * 8);
      {
        int row = m0 + tile * 16 + (l & 15);
        const u16* sh = Ah + (long)row * KDIM + kk;
        const u16* sl = Al + (long)row * KDIM + kk;
        *(short8*)&lds[0][e * 8] = *(const short8*)sh;
        *(short8*)&lds[1][e * 8] = *(const short8*)sl;
      }
      {
        int n = n0 + tile * 16 + (l & 15);
        long base;
        if (MODE == 0) {
          int tp = n >> 5; if (tp > TLAST) tp = TLAST;
          base = (long)(n & 31) * 131072 + (long)tp * 256;
        } else {
          base = (long)n * 256;
        }
        *(short8*)&lds[2][e * 8] = *(const short8*)(Bh + base + kk);
        *(short8*)&lds[3][e * 8] = *(const short8*)(Bl + base + kk);
      }
    }
    __syncthreads();
    short8 af[4][2], bf[4][2];
#pragma unroll
    for (int i = 0; i < 4; i++) {
      af[i][0] = *(const short8*)&lds[0][((wm * 4 + i) * 64 + lane) * 8];
      af[i][1] = *(const short8*)&lds[1][((wm * 4 + i) * 64 + lane) * 8];
      bf[i][0] = *(const short8*)&lds[2][((wn * 4 + i) * 64 + lane) * 8];
      bf[i][1] = *(const short8*)&lds[3][((wn * 4 + i) * 64 + lane) * 8];
    }
#pragma unroll
    for (int am = 0; am < 4; am++)
#pragma unroll
      for (int an = 0; an < 4; an++) {
        acc[am][an] = __builtin_amdgcn_mfma_f32_16x16x32_bf16(af[am][0], bf[an][0], acc[am][an], 0, 0, 0);
        acc[am][an] = __builtin_amdgcn_mfma_f32_16x16x32_bf16(af[am][0], bf[an][1], acc[am][an], 0, 0, 0);
        acc[am][an] = __builtin_amdgcn_mfma_f32_16x16x32_bf16(af[am][1], bf[an][0], acc[am][an], 0, 0, 0);
      }
  }
#pragma unroll
  for (int am = 0; am < 4; am++)
#pragma unroll
    for (int an = 0; an < 4; an++) {
      int n = n0 + (wn * 4 + an) * 16 + (lane & 15);
#pragma unroll
      for (int r = 0; r < 4; r++) {
        int m = m0 + (wm * 4 + am) * 16 + (lane >> 4) * 4 + r;
        float v = acc[am][an][r];
        if (MODE == 0) {
          float inv = e1[m] / sqrtf(e4[m] + 1e-5f);
          float sh  = e2[m] - e3[m] * inv;
          v = fmaxf(v + e0[m], 0.f) * inv + sh;
          u16 h, l; splitf(v, h, l);
          outh[(long)n * 256 + m] = h;
          outl[(long)n * 256 + m] = l;
        } else {
          v += e0[m] + e1[m];
          // scan layout: [2 grp][512 tp][32 sl][4 q][16 bb][16 jj]
          int tp = n >> 5, b = n & 31;
          int grp = b >> 4, bb = b & 15;
          int q = m >> 9, unit = m & 511;
          int sl = unit >> 4, jjj = unit & 15;
          outf[((((long)grp * 512 + tp) * 32 + sl) * 4 + q) * 256 + bb * 16 + jjj] = v;
        }
      }
    }
}

// ---------------- persistent skip-LSTM scan (2 groups x 16 batches, r5 protocol) ----------------
// 2 groups x 32 wgs; group = blockIdx&1, slot = blockIdx>>1. Group owns 16
// batches, wg owns 16 units (64 gate rows), W_hh pre-split in registers.
// GEOMETRY CHANGE vs r5: the 16x16 MFMA's B columns previously carried only 4
// distinct batches (4x redundant) forcing 8 groups / 256 wgs / 256 LLC poll
// streams. Consolidating to 16 batches/group fills all 16 columns with
// distinct batches at the SAME per-wave MFMA count (48) — r6's mistake
// (doubling serial MFMA) is avoided — and cuts poll streams 256->64 (the r4
// lever, poll congestion being the dominant term per r1/r4/r7).
// Protocol identical to r5: producer stores h u32 (lo LSB = marker
// mk(s)=((s>>1)&1)^1) then tagged parts u64, NO fence; consumers issue ONE
// speculative set of loads (16 u64 = 4 batch-rows, one producer) at staging
// entry; wave0 is the sole LLC poller (designated b=0 words, 2 lines/wg)
// relaying via LDS; waves 1-3 spin on LDS only; everything validated by
// tag/marker with reload-on-miss. Epilogue symmetric: all 64 lanes are cells
// (lane = bl*16+cj, batch cb = wave*4+bl). gpart padded [16][17] (r6-proven
// conflict fix). Overwrite-safety (parity-2): same induction — a wg passes
// its staging barrier only after certifying tag-s/mk(s-1) from ALL producers.
__global__ __launch_bounds__(256, 1) void scan_kernel(
    const float* __restrict__ xpg,    // [2][512][32][4][16][16]
    const float* __restrict__ w_hh,   // [2048][512]
    const float* __restrict__ w_uh,   // [512]
    const float* __restrict__ b_uh_p, // [1]
    uint32_t* __restrict__ hpk,       // [2][2][16][512] u32 (hi16|lo16, lo LSB = marker)
    u64* __restrict__ prt,            // [2][2][16][32] tagged
    float* __restrict__ outp)         // [32][512]
{
  __shared__ __attribute__((aligned(16))) u16 sh_hi[16 * 528];
  __shared__ __attribute__((aligned(16))) u16 sh_lo[16 * 528];
  __shared__ float gpart[4][4][16][17];  // [wave][q][unit][batch], pad 16->17
  __shared__ float sparts[16][32];
  __shared__ int   arrive_l[32];
  __shared__ float u_l[16], ubin_l[16];
  __shared__ float wuh_l[16];
  int group = blockIdx.x & 1, slot = blockIdx.x >> 1;
  int t = threadIdx.x;
  int wave = t >> 6, lane = t & 63;
  int um = lane & 15, kq = lane >> 4;

  if (t < 16) wuh_l[t] = w_uh[slot * 16 + t];
  if (t < 16) { u_l[t] = 1.0f; ubin_l[t] = 1.0f; }
  if (t < 32) arrive_l[t] = 0;

  // ---- preload W_hh fragments: wave w covers K[128w..128w+128) for gates 0..3
  short8 wfh[4][4], wfl[4][4];
#pragma unroll
  for (int q = 0; q < 4; q++) {
    long row = (long)(q * 512 + slot * 16 + um) * 512;
#pragma unroll
    for (int k4 = 0; k4 < 4; k4++) {
      union { short8 v; u16 u[8]; } Uh, Ul;
      long col0 = wave * 128 + k4 * 32 + kq * 8;
#pragma unroll
      for (int i = 0; i < 8; i++) splitf(w_hh[row + col0 + i], Uh.u[i], Ul.u[i]);
      wfh[q][k4] = Uh.v; wfl[q][k4] = Ul.v;
    }
  }
  float bu = b_uh_p[0];

  // epilogue mapping: every lane is a cell — batch cb = wave*4 + (lane>>4),
  // unit cj = lane&15 (so cj==um, bl==kq)
  int cb = wave * 4 + kq, cj = um;
  float c_reg = 0.f, h_reg = 0.f;

  uint32_t* hgrp = hpk + (long)group * 16384;  // [par][16 b][512 u] u32
  u64*      pgrp = prt + (long)group * 1024;   // [par][16 b][32 slot]

  __syncthreads();

  for (int s = 0; s < TP; s++) {
    int par = s & 1, np = par ^ 1;
    // xq for CURRENT step: all 64 lanes load their cell's 4 gate inputs
    f32x4 xq;
    {
      const float* xb = xpg + (((long)group * 512 + s) * 32 + slot) * 1024;
      xq = (f32x4){xb[0 * 256 + wave * 64 + lane],
                   xb[1 * 256 + wave * 64 + lane],
                   xb[2 * 256 + wave * 64 + lane],
                   xb[3 * 256 + wave * 64 + lane]};
    }
    // ---- stage h+parts: thread covers units (t&63)*8..+8 (producer (t&63)>>1)
    //      for 4 batch rows b0..b0+3 (b0 = (t>>6)*4) — one producer certifies all
    int b0 = (t >> 6) * 4, u0 = (t & 63) * 8;
    int pslot = (t & 63) >> 1;
    if (s == 0) {
#pragma unroll
      for (int bi = 0; bi < 4; bi++) {
        *(u32x4*)&sh_hi[(b0 + bi) * 528 + u0] = (u32x4){0u, 0u, 0u, 0u};
        *(u32x4*)&sh_lo[(b0 + bi) * 528 + u0] = (u32x4){0u, 0u, 0u, 0u};
      }
    } else {
      uint32_t tg = (uint32_t)s;
      uint32_t e = (((uint32_t)(s - 1) >> 1) & 1u) ^ 1u;   // expected marker mk(s-1)
      // this thread relays 2 of the 16 (b,slot) parts payloads
      int pb1 = b0 + ((t & 1) << 1), pb2 = pb1 + 1;
      const u64* pw1 = pgrp + (long)par * 512 + (long)pb1 * 32 + pslot;
      const u64* pw2 = pw1 + 32;
      // speculative one-shot issues (16 u64 h + 2 parts); self-validating
      u64 v[4][4];
#pragma unroll
      for (int bi = 0; bi < 4; bi++) {
        const u64* hp = (const u64*)(hgrp + (long)par * 8192 + (b0 + bi) * 512 + u0);
#pragma unroll
        for (int k = 0; k < 4; k++) v[bi][k] = AL(hp + k);
      }
      u64 w1 = AL(pw1), w2 = AL(pw2);
      if (t < 64) {
        // wave0: sole LLC poller on designated b=0 words (32 words = 2 lines)
        const u64* pd = pgrp + (long)par * 512 + pslot;
        u64 wd = AL(pd);
        while ((uint32_t)(wd >> 32) != tg) wd = AL(pd);
        if ((t & 1) == 0) ((volatile int*)arrive_l)[pslot] = s;  // LDS relay
      } else {
        // waves 1-3: LDS spin only (no LLC traffic); spec loads in flight
        volatile int* arr = (volatile int*)&arrive_l[pslot];
        while (*arr != s) {}
      }
      // parts payloads: spec value first, retry on stale (producer waves store
      // their 4 b-rows ~together with the designated word)
      while ((uint32_t)(w1 >> 32) != tg) w1 = AL(pw1);
      sparts[pb1][pslot] = __uint_as_float((uint32_t)w1);
      while ((uint32_t)(w2 >> 32) != tg) w2 = AL(pw2);
      sparts[pb2][pslot] = __uint_as_float((uint32_t)w2);
      // marker validation of speculative h; reload only on miss
      for (;;) {
        uint32_t bad = 0;
#pragma unroll
        for (int bi = 0; bi < 4; bi++)
#pragma unroll
          for (int k = 0; k < 4; k++)
            bad |= ((uint32_t)v[bi][k] ^ e) | ((uint32_t)(v[bi][k] >> 32) ^ e);
        if (!(bad & 1u)) break;
#pragma unroll
        for (int bi = 0; bi < 4; bi++) {
          const u64* hp = (const u64*)(hgrp + (long)par * 8192 + (b0 + bi) * 512 + u0);
#pragma unroll
          for (int k = 0; k < 4; k++) v[bi][k] = AL(hp + k);
        }
      }
#pragma unroll
      for (int bi = 0; bi < 4; bi++) {
        uint32_t p[8] = {(uint32_t)v[bi][0], (uint32_t)(v[bi][0] >> 32),
                         (uint32_t)v[bi][1], (uint32_t)(v[bi][1] >> 32),
                         (uint32_t)v[bi][2], (uint32_t)(v[bi][2] >> 32),
                         (uint32_t)v[bi][3], (uint32_t)(v[bi][3] >> 32)};
        u32x4 hv, lv;
#pragma unroll
        for (int r = 0; r < 4; r++) {
          hv[r] = __builtin_amdgcn_perm(p[2 * r + 1], p[2 * r], 0x07060302u);
          lv[r] = __builtin_amdgcn_perm(p[2 * r + 1], p[2 * r], 0x05040100u);
        }
        *(u32x4*)&sh_hi[(b0 + bi) * 528 + u0] = hv;
        *(u32x4*)&sh_lo[(b0 + bi) * 528 + u0] = lv;
      }
    }
    __syncthreads();   // staged data visible; also orders vs prev epilogue LDS reads
    // ---- u-update (t<16) from staged parts; identical fixed order in all 32 wgs
    if (s > 0 && t < 16) {
      float a = 0.f;
#pragma unroll
      for (int i = 0; i < 32; i++) a += sparts[t][i];
      float du = sigm(a + bu);
      float up = u_l[t], ubp = ubin_l[t];
      float un = (ubp > 0.5f) ? du : (up + fminf(du, 1.f - up));
      u_l[t] = un; ubin_l[t] = rintf(un);
    }
    // ---- MFMA: wave w does its K-quarter for all 4 gates; B cols = 16 batches
    f32x4 A0[4], A1[4], A2[4];
#pragma unroll
    for (int q = 0; q < 4; q++) {
      A0[q] = (f32x4){0.f, 0.f, 0.f, 0.f}; A1[q] = A0[q]; A2[q] = A0[q];
    }
#pragma unroll
    for (int k4 = 0; k4 < 4; k4++) {
      int ko = (wave * 4 + k4) * 32 + kq * 8;
      short8 bh = *(const short8*)&sh_hi[um * 528 + ko];
      short8 bl = *(const short8*)&sh_lo[um * 528 + ko];
#pragma unroll
      for (int q = 0; q < 4; q++) {
        A0[q] = __builtin_amdgcn_mfma_f32_16x16x32_bf16(wfh[q][k4], bh, A0[q], 0, 0, 0);
        A1[q] = __builtin_amdgcn_mfma_f32_16x16x32_bf16(wfh[q][k4], bl, A1[q], 0, 0, 0);
        A2[q] = __builtin_amdgcn_mfma_f32_16x16x32_bf16(wfl[q][k4], bh, A2[q], 0, 0, 0);
      }
    }
    {
#pragma unroll
      for (int q = 0; q < 4; q++)
#pragma unroll
        for (int r = 0; r < 4; r++)
          gpart[wave][q][kq * 4 + r][um] = (A0[q][r] + A1[q][r]) + A2[q][r];
    }
    __syncthreads();
    // ---- epilogue: all 64 lanes — one cell each (batch cb, unit slot*16+cj)
    {
      float g[4];
#pragma unroll
      for (int q = 0; q < 4; q++) {
        float a = xq[q];
#pragma unroll
        for (int w = 0; w < 4; w++) a += gpart[w][q][cj][cb];
        g[q] = a;
      }
      float ig = sigm(g[0]), fg = sigm(g[1]), og = sigm(g[3]);
      float gt = tanh_fast(g[2]);
      float ct = fg * c_reg + ig * gt;
      float ht = og * tanh_fast(ct);
      bool upd = ubin_l[cb] > 0.5f;
      float cn = upd ? ct : c_reg;
      float hn = upd ? ht : h_reg;
      c_reg = cn; h_reg = hn;
      u16 hhi, hlo; splitf(hn, hhi, hlo);
      // generation marker in lo LSB (~2^-15 relative perturbation, << tolerance)
      uint32_t mk = (((uint32_t)s >> 1) & 1u) ^ 1u;
      hlo = (u16)((hlo & 0xFFFEu) | mk);
      uint32_t pk = ((uint32_t)hhi << 16) | (uint32_t)hlo;
      // untagged h store: 16-lane runs contiguous -> 4x64B chunks/wave; NO fence
      __hip_atomic_store(hgrp + (long)np * 8192 + cb * 512 + slot * 16 + cj, pk,
                         __ATOMIC_RELAXED, __HIP_MEMORY_SCOPE_AGENT);
      float pr = cn * wuh_l[cj];
      pr += __shfl_xor(pr, 1); pr += __shfl_xor(pr, 2);
      pr += __shfl_xor(pr, 4); pr += __shfl_xor(pr, 8);   // within 16-lane group
      if (s == TLAST) outp[(long)(group * 16 + cb) * 512 + slot * 16 + cj] = hn;
      if (cj == 0) {
        u64 pwv = ((u64)(uint32_t)(s + 1) << 32) | (u64)__float_as_uint(pr);
        __hip_atomic_store(pgrp + (long)np * 512 + cb * 32 + slot, pwv,
                           __ATOMIC_RELAXED, __HIP_MEMORY_SCOPE_AGENT);
      }
    }
    // no barrier: next staging (sh writes) is safe — all frag reads preceded the
    // gpart barrier; each wave's gpart reads precede its own next-iter barrier#1.
  }
}

// ---------------- launcher ----------------
extern "C" void kernel_launch(void* const* d_in, const int* in_sizes, int n_in,
                              void* d_out, int out_size, void* d_ws, size_t ws_size,
                              hipStream_t stream) {
  const float* x      = (const float*)d_in[0];
  const float* conv_w = (const float*)d_in[1];
  const float* conv_b = (const float*)d_in[2];
  const float* gamma  = (const float*)d_in[3];
  const float* beta   = (const float*)d_in[4];
  const float* mean   = (const float*)d_in[5];
  const float* var    = (const float*)d_in[6];
  const float* w_ih   = (const float*)d_in[7];
  const float* w_hh   = (const float*)d_in[8];
  const float* b_ih   = (const float*)d_in[9];
  const float* b_hh   = (const float*)d_in[10];
  const float* w_uh   = (const float*)d_in[11];
  const float* b_uh   = (const float*)d_in[12];
  float* out = (float*)d_out;

  if (ws_size < WS_NEED) return;  // workspace too small: fail visibly via absmax

  char* w = (char*)d_ws;
  uint32_t* hpk = (uint32_t*)(w + HPK_OFF);
  u64*   prt   = (u64*)(w + PRT_OFF);
  float* xp    = (float*)(w + XP_OFF);
  u16*   xh    = (u16*)(w + XH_OFF);
  u16*   xl    = (u16*)(w + XL_OFF);
  u16*   xsh   = (u16*)(w + XSH_OFF);
  u16*   xsl   = (u16*)(w + XSL_OFF);
  u16*   wch   = (u16*)(w + WCH_OFF);
  u16*   wcl   = (u16*)(w + WCL_OFF);
  u16*   wihh  = (u16*)(w + WIHH_OFF);
  u16*   wihl  = (u16*)(w + WIHL_OFF);

  // no memset: parts tags self-validate and h markers reject 0xAA poison
  // (poison LSB=0 != expected marker 1 for the first two reads of each cell).

  prep_kernel<<<19072, 256, 0, stream>>>(x, conv_w, w_ih, xh, xl, wch, wcl, wihh, wihl);

  // conv GEMM: M=256(f) N=16384 K=640 -> xs (relu+BN, bf16 hi/lo, [n][f])
  gemm_kernel<0><<<2 * 128, 256, 0, stream>>>(wch, wcl, xh, xl,
                                              conv_b, gamma, beta, mean, var,
                                              xsh, xsl, nullptr);
  // proj GEMM: M=2048(g) N=16384 K=256 -> xp fp32 scan-coalesced (+ b_ih + b_hh)
  gemm_kernel<1><<<16 * 128, 256, 0, stream>>>(wihh, wihl, xsh, xsl,
                                               b_ih, b_hh, nullptr, nullptr, nullptr,
                                               nullptr, nullptr, xp);
  // persistent scan: 2 groups x 32 wgs (16 batches/group), r5 protocol
  scan_kernel<<<GWG, 256, 0, stream>>>(xp, w_hh, w_uh, b_uh, hpk, prt, out);
}

// Round 10
// 1703.640 us; speedup vs baseline: 1.1757x; 1.1757x over previous
//
#include <hip/hip_runtime.h>
#include <stdint.h>
#include <math.h>

// ---------------- problem constants ----------------
#define BB 32
#define TT 1024
#define CIN 128
#define FF 256
#define KW 5
#define HH 512
#define TP 510          // conv output length (VALID, stride 2)
#define TLAST 509
#define KC 640          // conv GEMM K  (5*128)
#define GWG 256         // scan workgroups: 8 groups x 32 wgs

// ---------------- workspace layout (bytes) ----------------
// parts words tagged (tag<<32|payload): 0xAA poison never matches tags 1..510.
// h words u32 (hi16|lo16) with lo LSB = generation marker ((s>>1)&1)^1 —
// consumer validates markers after the bulk load, so the producer needs NO
// store-ack fence, and consumers may load SPECULATIVELY before detection.
#define HPK_OFF     0ull          // h u32: [8 grp][par2][4b][512u] = 131072 (region reserves 262144)
#define PRT_OFF     262144ull     // parts u64: [8 grp][par2][4b][32wg] = 16384
#define XP_OFF      278528ull                         // fp32 [8grp][512 t'][32 slot][4q][16jj][4b] = 134217728
#define XH_OFF      (XP_OFF + 134217728ull)           // x hi bf16 [4194304]
#define XL_OFF      (XH_OFF + 8388608ull)
#define XSH_OFF     (XL_OFF + 8388608ull)             // xs hi bf16 [16384][256]
#define XSL_OFF     (XSH_OFF + 8388608ull)
#define WCH_OFF     (XSL_OFF + 8388608ull)            // conv W [256][640] hi
#define WCL_OFF     (WCH_OFF + 327680ull)
#define WIHH_OFF    (WCL_OFF + 327680ull)             // w_ih [2048][256] hi
#define WIHL_OFF    (WIHH_OFF + 1048576ull)
#define WS_NEED     (WIHL_OFF + 1048576ull)           // ~163.6 MiB

typedef unsigned short u16;
typedef unsigned long long u64;
typedef __attribute__((ext_vector_type(8))) short short8;
typedef __attribute__((ext_vector_type(4))) float f32x4;
typedef __attribute__((ext_vector_type(4))) unsigned int u32x4;

__device__ __forceinline__ u16 f2bf(float f) {
  uint32_t u = __float_as_uint(f);
  u += 0x7fffu + ((u >> 16) & 1u);      // RNE
  return (u16)(u >> 16);
}
__device__ __forceinline__ float bf2f(u16 s) { return __uint_as_float(((uint32_t)s) << 16); }
__device__ __forceinline__ void splitf(float v, u16& h, u16& l) {
  h = f2bf(v);
  l = f2bf(v - bf2f(h));
}
// fast transcendentals (v_exp_f32 path, ~1 ulp): keeps the scan epilogue's
// critical path free of branchy libm calls. Gate perturbation ~1e-6 << margin.
__device__ __forceinline__ float sigm(float x) {
  return __fdividef(1.f, 1.f + __expf(-x));
}
__device__ __forceinline__ float tanh_fast(float x) {
  float xc = fminf(x, 20.f);             // avoid inf/inf for large +x (tanh==1 there)
  float e = __expf(2.f * xc);
  return (e - 1.f) * __fdividef(1.f, e + 1.f);
}

// ---------------- prep: split x / conv_w(transposed) / w_ih into bf16 hi+lo ----------------
__global__ void prep_kernel(const float* __restrict__ x, const float* __restrict__ conv_w,
                            const float* __restrict__ w_ih,
                            u16* __restrict__ xh, u16* __restrict__ xl,
                            u16* __restrict__ wch, u16* __restrict__ wcl,
                            u16* __restrict__ wihh, u16* __restrict__ wihl) {
  int i = blockIdx.x * 256 + threadIdx.x;
  if (i < 4194304) {
    u16 h, l; splitf(x[i], h, l); xh[i] = h; xl[i] = l;
  } else if (i < 4194304 + 163840) {
    int j = i - 4194304;
    int f = j / 640, kk = j % 640;
    int c = kk & 127, k = kk >> 7;                 // kk = k*128 + c
    u16 h, l; splitf(conv_w[f * 640 + c * 5 + k], h, l);
    wch[f * 640 + kk] = h; wcl[f * 640 + kk] = l;
  } else if (i < 4194304 + 163840 + 524288) {
    int j = i - (4194304 + 163840);
    u16 h, l; splitf(w_ih[j], h, l); wihh[j] = h; wihl[j] = l;
  }
}

// ---------------- split-bf16 GEMM, 128x128 tile, BK=32, frag-order LDS ----------------
// MODE 0: conv  (K=640, B = windowed x, epilogue relu+BN -> xs hi/lo bf16 at [n][f])
// MODE 1: proj  (K=256, B = xs rows,    epilogue +bias   -> xp fp32, scan-coalesced layout)
template <int MODE>
__global__ __launch_bounds__(256, 1) void gemm_kernel(
    const u16* __restrict__ Ah, const u16* __restrict__ Al,
    const u16* __restrict__ Bh, const u16* __restrict__ Bl,
    const float* __restrict__ e0, const float* __restrict__ e1,
    const float* __restrict__ e2, const float* __restrict__ e3, const float* __restrict__ e4,
    u16* __restrict__ outh, u16* __restrict__ outl, float* __restrict__ outf) {
  const int KDIM = (MODE == 0) ? KC : 256;
  const int MT   = (MODE == 0) ? 2 : 16;
  int bx = blockIdx.x;
  int m0 = (bx % MT) * 128;
  int n0 = (bx / MT) * 128;
  __shared__ __attribute__((aligned(16))) u16 lds[4][4096];
  int t = threadIdx.x;
  int wave = t >> 6, lane = t & 63;
  int wm = wave & 1, wn = wave >> 1;

  f32x4 acc[4][4];
#pragma unroll
  for (int i = 0; i < 4; i++)
#pragma unroll
    for (int j = 0; j < 4; j++) acc[i][j] = (f32x4){0.f, 0.f, 0.f, 0.f};

  for (int k0 = 0; k0 < KDIM; k0 += 32) {
    __syncthreads();
#pragma unroll
    for (int half = 0; half < 2; half++) {
      int e = half * 256 + t;
      int l = e & 63, tile = e >> 6;
      int kk = k0 + ((l >> 4) * 8);
      {
        int row = m0 + tile * 16 + (l & 15);
        const u16* sh = Ah + (long)row * KDIM + kk;
        const u16* sl = Al + (long)row * KDIM + kk;
        *(short8*)&lds[0][e * 8] = *(const short8*)sh;
        *(short8*)&lds[1][e * 8] = *(const short8*)sl;
      }
      {
        int n = n0 + tile * 16 + (l & 15);
        long base;
        if (MODE == 0) {
          int tp = n >> 5; if (tp > TLAST) tp = TLAST;
          base = (long)(n & 31) * 131072 + (long)tp * 256;
        } else {
          base = (long)n * 256;
        }
        *(short8*)&lds[2][e * 8] = *(const short8*)(Bh + base + kk);
        *(short8*)&lds[3][e * 8] = *(const short8*)(Bl + base + kk);
      }
    }
    __syncthreads();
    short8 af[4][2], bf[4][2];
#pragma unroll
    for (int i = 0; i < 4; i++) {
      af[i][0] = *(const short8*)&lds[0][((wm * 4 + i) * 64 + lane) * 8];
      af[i][1] = *(const short8*)&lds[1][((wm * 4 + i) * 64 + lane) * 8];
      bf[i][0] = *(const short8*)&lds[2][((wn * 4 + i) * 64 + lane) * 8];
      bf[i][1] = *(const short8*)&lds[3][((wn * 4 + i) * 64 + lane) * 8];
    }
#pragma unroll
    for (int am = 0; am < 4; am++)
#pragma unroll
      for (int an = 0; an < 4; an++) {
        acc[am][an] = __builtin_amdgcn_mfma_f32_16x16x32_bf16(af[am][0], bf[an][0], acc[am][an], 0, 0, 0);
        acc[am][an] = __builtin_amdgcn_mfma_f32_16x16x32_bf16(af[am][0], bf[an][1], acc[am][an], 0, 0, 0);
        acc[am][an] = __builtin_amdgcn_mfma_f32_16x16x32_bf16(af[am][1], bf[an][0], acc[am][an], 0, 0, 0);
      }
  }
#pragma unroll
  for (int am = 0; am < 4; am++)
#pragma unroll
    for (int an = 0; an < 4; an++) {
      int n = n0 + (wn * 4 + an) * 16 + (lane & 15);
#pragma unroll
      for (int r = 0; r < 4; r++) {
        int m = m0 + (wm * 4 + am) * 16 + (lane >> 4) * 4 + r;
        float v = acc[am][an][r];
        if (MODE == 0) {
          float inv = e1[m] / sqrtf(e4[m] + 1e-5f);
          float sh  = e2[m] - e3[m] * inv;
          v = fmaxf(v + e0[m], 0.f) * inv + sh;
          u16 h, l; splitf(v, h, l);
          outh[(long)n * 256 + m] = h;
          outl[(long)n * 256 + m] = l;
        } else {
          v += e0[m] + e1[m];
          int tp = n >> 5, b = n & 31;
          int grp = b >> 2, bb = b & 3;
          int q = m >> 9, unit = m & 511;
          int sl = unit >> 4, jjj = unit & 15;
          outf[(((long)grp * 512 + tp) * 32 + sl) * 256 + q * 64 + jjj * 4 + bb] = v;
        }
      }
    }
}

// ---------------- persistent skip-LSTM scan (r5/r8 structure — session optimum) ----------------
// 8 groups x 32 wgs; group = blockIdx&7, slot = blockIdx>>3. Group owns batches
// [4g,4g+4); wg owns 16 units, W_hh pre-split in registers.
// Session laws (validated over 10 rounds):
//  (1) Step latency is a monotone function of background LLC request rate:
//      r1 (+16x poll width) +50%; r7 (re-spec/stagger) +39%; r9 (4x spec
//      width) +16%. Keep exactly ONE poll stream/wg and ONE spec set.
//  (2) Never trade per-wave serial compute for fewer producers: r6 +24%.
//  (3) Wins: r4 single-poller+LDS relay (-17%); r5 speculative self-validating
//      loads + symmetric epilogue (-10%); traffic-neutral LDS pad (r8).
// Protocol: producer stores h u32 (lo LSB = marker mk(s)=((s>>1)&1)^1) then
// tagged parts u64, NO fence; consumers issue ONE speculative set of loads at
// staging entry; wave0 is the SOLE LLC poller (2 lines/wg) relaying via LDS;
// waves1-3 spin on LDS only; tag/marker validation with reload-on-miss.
// Overwrite safety (parity-2): a wg passes staging s only after certifying
// tag-s/mk(s-1) from ALL producers, each of which passed staging s-1 -> the
// parity buffer overwritten at end of step s is dead. Poison 0xAA rejected by
// tag (never 1..510) and marker (LSB 0 != expected 1 on first two reads).
// Structural floor: 510 serial MALL exchanges x ~2RT ~= 1.2-1.4 ms; this scan
// runs within ~15% of that. MfmaUtil/HBM% confirm latency-bound, not resource.
__global__ __launch_bounds__(256, 1) void scan_kernel(
    const float* __restrict__ xpg,    // [8][512][32][256]
    const float* __restrict__ w_hh,   // [2048][512]
    const float* __restrict__ w_uh,   // [512]
    const float* __restrict__ b_uh_p, // [1]
    uint32_t* __restrict__ hpk,       // [8][2][4][512] u32 (hi16|lo16, lo LSB = marker)
    u64* __restrict__ prt,            // [8][2][4][32] tagged
    float* __restrict__ outp)         // [32][512]
{
  __shared__ __attribute__((aligned(16))) u16 sh_hi[4 * 528];
  __shared__ __attribute__((aligned(16))) u16 sh_lo[4 * 528];
  __shared__ float gpart[4][4][16][5];   // pad 4->5: conflict-free (r6/r7-proven)
  __shared__ float sparts[4][32];
  __shared__ int   arrive_l[32];
  __shared__ float u_l[4], ubin_l[4];
  __shared__ float wuh_l[16];
  int group = blockIdx.x & 7, slot = blockIdx.x >> 3;
  int t = threadIdx.x;
  int wave = t >> 6, lane = t & 63;
  int um = lane & 15, kq = lane >> 4;
  int nbc = um & 3;

  if (t < 16) wuh_l[t] = w_uh[slot * 16 + t];
  if (t < 4)  { u_l[t] = 1.0f; ubin_l[t] = 1.0f; }
  if (t < 32) arrive_l[t] = 0;

  // ---- preload W_hh fragments: wave w covers K[128w..128w+128) for gates 0..3
  short8 wfh[4][4], wfl[4][4];
#pragma unroll
  for (int q = 0; q < 4; q++) {
    long row = (long)(q * 512 + slot * 16 + um) * 512;
#pragma unroll
    for (int k4 = 0; k4 < 4; k4++) {
      union { short8 v; u16 u[8]; } Uh, Ul;
      long col0 = wave * 128 + k4 * 32 + kq * 8;
#pragma unroll
      for (int i = 0; i < 8; i++) splitf(w_hh[row + col0 + i], Uh.u[i], Ul.u[i]);
      wfh[q][k4] = Uh.v; wfl[q][k4] = Ul.v;
    }
  }
  float bu = b_uh_p[0];

  // symmetric epilogue mapping: wave = batch cb, lanes 0-15 = unit cj
  bool cell = (lane < 16);
  int  cb = wave, cj = lane;
  float c_reg = 0.f, h_reg = 0.f;

  uint32_t* hgrp = hpk + (long)group * 4096;   // [par][4b][512] u32
  u64*      pgrp = prt + (long)group * 256;    // [par][4b][32]

  __syncthreads();

  for (int s = 0; s < TP; s++) {
    int par = s & 1, np = par ^ 1;
    // xq for CURRENT step: each wave's cell lanes load their batch's gate inputs
    f32x4 xq;
    if (cell) {
      const float* xb = xpg + (((long)group * 512 + s) * 32 + slot) * 256;
      float x0 = xb[0 * 64 + cj * 4 + cb];
      float x1 = xb[1 * 64 + cj * 4 + cb];
      float x2 = xb[2 * 64 + cj * 4 + cb];
      float x3 = xb[3 * 64 + cj * 4 + cb];
      xq = (f32x4){x0, x1, x2, x3};
    }
    // ---- stage h+parts (thread covers batch b=t>>6, units (t&63)*8..+8)
    int b = t >> 6, u0 = (t & 63) * 8;
    if (s == 0) {
      *(u32x4*)&sh_hi[b * 528 + u0] = (u32x4){0u, 0u, 0u, 0u};
      *(u32x4*)&sh_lo[b * 528 + u0] = (u32x4){0u, 0u, 0u, 0u};
    } else {
      int pslot = (t & 63) >> 1;
      const u64* pw = pgrp + (long)par * 128 + b * 32 + pslot;
      const u64* hp = (const u64*)(hgrp + (long)par * 2048 + b * 512 + u0);
      uint32_t tg = (uint32_t)s;
      uint32_t e = (((uint32_t)(s - 1) >> 1) & 1u) ^ 1u;   // expected marker mk(s-1)
      bool needp = ((t & 1) == 0);
      // speculative one-shot issues: latency overlaps the arrival wait below;
      // values self-validate (tag / marker), so no ordering assumption is made
      u64 v0 = __hip_atomic_load(hp,     __ATOMIC_RELAXED, __HIP_MEMORY_SCOPE_AGENT);
      u64 v1 = __hip_atomic_load(hp + 1, __ATOMIC_RELAXED, __HIP_MEMORY_SCOPE_AGENT);
      u64 v2 = __hip_atomic_load(hp + 2, __ATOMIC_RELAXED, __HIP_MEMORY_SCOPE_AGENT);
      u64 v3 = __hip_atomic_load(hp + 3, __ATOMIC_RELAXED, __HIP_MEMORY_SCOPE_AGENT);
      u64 w0 = 0;
      if (b == 0 || needp)
        w0 = __hip_atomic_load(pw, __ATOMIC_RELAXED, __HIP_MEMORY_SCOPE_AGENT);
      if (b == 0) {
        // wave0: sole LLC poller; single serial stream; spec value checked first
        u64 w = w0;
        while ((uint32_t)(w >> 32) != tg)
          w = __hip_atomic_load(pw, __ATOMIC_RELAXED, __HIP_MEMORY_SCOPE_AGENT);
        if (needp) {
          sparts[0][pslot] = __uint_as_float((uint32_t)w);
          ((volatile int*)arrive_l)[pslot] = s;       // LDS relay to waves 1-3
        }
      } else {
        // waves 1-3: LDS spin (no LLC traffic); spec loads in flight meanwhile
        volatile int* arr = (volatile int*)&arrive_l[pslot];
        while (*arr != s) {}
        if (needp) {
          u64 w = w0;                                  // spec parts, retry on stale
          while ((uint32_t)(w >> 32) != tg)
            w = __hip_atomic_load(pw, __ATOMIC_RELAXED, __HIP_MEMORY_SCOPE_AGENT);
          sparts[b][pslot] = __uint_as_float((uint32_t)w);
        }
      }
      // marker validation of speculative h; reload only on miss
      for (;;) {
        uint32_t bad = (((uint32_t)v0 ^ e) | ((uint32_t)(v0 >> 32) ^ e) |
                        ((uint32_t)v1 ^ e) | ((uint32_t)(v1 >> 32) ^ e) |
                        ((uint32_t)v2 ^ e) | ((uint32_t)(v2 >> 32) ^ e) |
                        ((uint32_t)v3 ^ e) | ((uint32_t)(v3 >> 32) ^ e)) & 1u;
        if (!bad) break;
        v0 = __hip_atomic_load(hp,     __ATOMIC_RELAXED, __HIP_MEMORY_SCOPE_AGENT);
        v1 = __hip_atomic_load(hp + 1, __ATOMIC_RELAXED, __HIP_MEMORY_SCOPE_AGENT);
        v2 = __hip_atomic_load(hp + 2, __ATOMIC_RELAXED, __HIP_MEMORY_SCOPE_AGENT);
        v3 = __hip_atomic_load(hp + 3, __ATOMIC_RELAXED, __HIP_MEMORY_SCOPE_AGENT);
      }
      uint32_t p[8] = {(uint32_t)v0, (uint32_t)(v0 >> 32), (uint32_t)v1, (uint32_t)(v1 >> 32),
                       (uint32_t)v2, (uint32_t)(v2 >> 32), (uint32_t)v3, (uint32_t)(v3 >> 32)};
      u32x4 hv, lv;
#pragma unroll
      for (int r = 0; r < 4; r++) {
        hv[r] = __builtin_amdgcn_perm(p[2 * r + 1], p[2 * r], 0x07060302u);
        lv[r] = __builtin_amdgcn_perm(p[2 * r + 1], p[2 * r], 0x05040100u);
      }
      *(u32x4*)&sh_hi[b * 528 + u0] = hv;
      *(u32x4*)&sh_lo[b * 528 + u0] = lv;
    }
    __syncthreads();   // staged data visible; also orders vs prev epilogue LDS reads
    // ---- u-update (t<4) from staged parts; identical fixed order in all 32 wgs
    if (s > 0 && t < 4) {
      float a = 0.f;
#pragma unroll
      for (int i = 0; i < 32; i++) a += sparts[t][i];
      float du = sigm(a + bu);
      float up = u_l[t], ubp = ubin_l[t];
      float un = (ubp > 0.5f) ? du : (up + fminf(du, 1.f - up));
      u_l[t] = un; ubin_l[t] = rintf(un);
    }
    // ---- MFMA: wave w does its K-quarter for all 4 gates (12 indep chains)
    f32x4 A0[4], A1[4], A2[4];
#pragma unroll
    for (int q = 0; q < 4; q++) {
      A0[q] = (f32x4){0.f, 0.f, 0.f, 0.f}; A1[q] = A0[q]; A2[q] = A0[q];
    }
#pragma unroll
    for (int k4 = 0; k4 < 4; k4++) {
      int ko = (wave * 4 + k4) * 32 + kq * 8;
      short8 bh = *(const short8*)&sh_hi[nbc * 528 + ko];
      short8 bl = *(const short8*)&sh_lo[nbc * 528 + ko];
#pragma unroll
      for (int q = 0; q < 4; q++) {
        A0[q] = __builtin_amdgcn_mfma_f32_16x16x32_bf16(wfh[q][k4], bh, A0[q], 0, 0, 0);
        A1[q] = __builtin_amdgcn_mfma_f32_16x16x32_bf16(wfh[q][k4], bl, A1[q], 0, 0, 0);
        A2[q] = __builtin_amdgcn_mfma_f32_16x16x32_bf16(wfl[q][k4], bh, A2[q], 0, 0, 0);
      }
    }
    if (um < 4) {
#pragma unroll
      for (int q = 0; q < 4; q++)
#pragma unroll
        for (int r = 0; r < 4; r++)
          gpart[wave][q][kq * 4 + r][um] = (A0[q][r] + A1[q][r]) + A2[q][r];
    }
    __syncthreads();
    // ---- epilogue: symmetric — wave cb handles batch cb's 16 cells
    if (cell) {
      float g[4];
#pragma unroll
      for (int q = 0; q < 4; q++) {
        float a = xq[q];
#pragma unroll
        for (int w = 0; w < 4; w++) a += gpart[w][q][cj][cb];
        g[q] = a;
      }
      float ig = sigm(g[0]), fg = sigm(g[1]), og = sigm(g[3]);
      float gt = tanh_fast(g[2]);
      float ct = fg * c_reg + ig * gt;
      float ht = og * tanh_fast(ct);
      bool upd = ubin_l[cb] > 0.5f;
      float cn = upd ? ct : c_reg;
      float hn = upd ? ht : h_reg;
      c_reg = cn; h_reg = hn;
      u16 hhi, hlo; splitf(hn, hhi, hlo);
      // generation marker in lo LSB (~2^-15 relative perturbation, << tolerance)
      uint32_t mk = (((uint32_t)s >> 1) & 1u) ^ 1u;
      hlo = (u16)((hlo & 0xFFFEu) | mk);
      uint32_t pk = ((uint32_t)hhi << 16) | (uint32_t)hlo;
      // untagged h store: 16 lanes contiguous -> one 64B chunk per wave; NO fence
      __hip_atomic_store(hgrp + (long)np * 2048 + cb * 512 + slot * 16 + cj, pk,
                         __ATOMIC_RELAXED, __HIP_MEMORY_SCOPE_AGENT);
      float pr = cn * wuh_l[cj];
      pr += __shfl_xor(pr, 1); pr += __shfl_xor(pr, 2);
      pr += __shfl_xor(pr, 4); pr += __shfl_xor(pr, 8);
      if (s == TLAST) outp[(long)(group * 4 + cb) * 512 + slot * 16 + cj] = hn;
      if (cj == 0) {
        u64 pw = ((u64)(uint32_t)(s + 1) << 32) | (u64)__float_as_uint(pr);
        __hip_atomic_store(pgrp + (long)np * 128 + cb * 32 + slot, pw,
                           __ATOMIC_RELAXED, __HIP_MEMORY_SCOPE_AGENT);
      }
    }
    // no barrier: next staging (sh writes) is safe — all frag reads preceded the
    // gpart barrier; each wave's gpart reads precede its own next-iter barrier#1.
  }
}

// ---------------- launcher ----------------
extern "C" void kernel_launch(void* const* d_in, const int* in_sizes, int n_in,
                              void* d_out, int out_size, void* d_ws, size_t ws_size,
                              hipStream_t stream) {
  const float* x      = (const float*)d_in[0];
  const float* conv_w = (const float*)d_in[1];
  const float* conv_b = (const float*)d_in[2];
  const float* gamma  = (const float*)d_in[3];
  const float* beta   = (const float*)d_in[4];
  const float* mean   = (const float*)d_in[5];
  const float* var    = (const float*)d_in[6];
  const float* w_ih   = (const float*)d_in[7];
  const float* w_hh   = (const float*)d_in[8];
  const float* b_ih   = (const float*)d_in[9];
  const float* b_hh   = (const float*)d_in[10];
  const float* w_uh   = (const float*)d_in[11];
  const float* b_uh   = (const float*)d_in[12];
  float* out = (float*)d_out;

  if (ws_size < WS_NEED) return;  // workspace too small: fail visibly via absmax

  char* w = (char*)d_ws;
  uint32_t* hpk = (uint32_t*)(w + HPK_OFF);
  u64*   prt   = (u64*)(w + PRT_OFF);
  float* xp    = (float*)(w + XP_OFF);
  u16*   xh    = (u16*)(w + XH_OFF);
  u16*   xl    = (u16*)(w + XL_OFF);
  u16*   xsh   = (u16*)(w + XSH_OFF);
  u16*   xsl   = (u16*)(w + XSL_OFF);
  u16*   wch   = (u16*)(w + WCH_OFF);
  u16*   wcl   = (u16*)(w + WCL_OFF);
  u16*   wihh  = (u16*)(w + WIHH_OFF);
  u16*   wihl  = (u16*)(w + WIHL_OFF);

  // no memset: parts tags self-validate and h markers reject 0xAA poison
  // (poison LSB=0 != expected marker 1 for the first two reads of each cell).

  prep_kernel<<<19072, 256, 0, stream>>>(x, conv_w, w_ih, xh, xl, wch, wcl, wihh, wihl);

  // conv GEMM: M=256(f) N=16384 K=640 -> xs (relu+BN, bf16 hi/lo, [n][f])
  gemm_kernel<0><<<2 * 128, 256, 0, stream>>>(wch, wcl, xh, xl,
                                              conv_b, gamma, beta, mean, var,
                                              xsh, xsl, nullptr);
  // proj GEMM: M=2048(g) N=16384 K=256 -> xp fp32 scan-coalesced (+ b_ih + b_hh)
  gemm_kernel<1><<<16 * 128, 256, 0, stream>>>(wihh, wihl, xsh, xsl,
                                               b_ih, b_hh, nullptr, nullptr, nullptr,
                                               nullptr, nullptr, xp);
  // persistent scan: 8 groups x 32 wgs (r5/r8 structure — session optimum)
  scan_kernel<<<GWG, 256, 0, stream>>>(xp, w_hh, w_uh, b_uh, hpk, prt, out);
}